// Round 3
// baseline (11455.721 us; speedup 1.0000x reference)
//
#include <hip/hip_runtime.h>

#define TT   365
#define BTOT 2048
#define DIN  32
#define SIN  27
#define HD   256
#define G3   768
#define BLOCK 256
#define ZBUF 2560                       // 4 h-octet groups (2048B) + x group (512B)
#define WS_WIH   (G3*HD*2)              // 393216
#define WS_FLAGS (WS_WIH + G3*DIN*2)    // 442368
#define WS_PUB   (WS_FLAGS + 4096)      // 446464 ; + 512*2*2048 = 2.43 MB total

typedef float  f32x4  __attribute__((ext_vector_type(4)));
typedef short  bf16x8 __attribute__((ext_vector_type(8)));

__device__ __forceinline__ unsigned short f2bf(float f) {
  unsigned u = __builtin_bit_cast(unsigned, f);
  u += 0x7fffu + ((u >> 16) & 1u);          // RNE to bf16
  return (unsigned short)(u >> 16);
}
__device__ __forceinline__ float bf2f(unsigned short u) {
  unsigned v = ((unsigned)u) << 16;
  return __builtin_bit_cast(float, v);
}
__device__ __forceinline__ float fsig(float x) {
  float e = __builtin_amdgcn_exp2f(x * -1.442695040888963f);
  return __builtin_amdgcn_rcpf(1.0f + e);
}
__device__ __forceinline__ float ftanh(float x) {
  float e = __builtin_amdgcn_exp2f(x * 2.885390081777927f); // e^{2x}
  return 1.0f - 2.0f * __builtin_amdgcn_rcpf(1.0f + e);
}

__global__ void prep_kernel(const float* __restrict__ whh, const float* __restrict__ wih,
                            unsigned short* __restrict__ whh_bf,
                            unsigned short* __restrict__ wih_bf) {
  int stride = gridDim.x * blockDim.x;
  int i0 = blockIdx.x * blockDim.x + threadIdx.x;
  for (int i = i0; i < G3 * HD;  i += stride) whh_bf[i] = f2bf(whh[i]);
  for (int i = i0; i < G3 * DIN; i += stride) wih_bf[i] = f2bf(wih[i]);
}

// Pair-split: blocks 2p / 2p+1 share batch rows [8p, 8p+8); even block owns
// h-cols 0..127, odd owns 128..255. Own half lives in LDS (frag layout);
// per step each block publishes its half to d_ws (LLC) and reads the
// partner half as MFMA A-fragments. Flag protocol: flag[bid]=t+1 after
// h(t+1) published; spin partner>=t at step t. 2 blocks/CU -> pipe overlap.
__global__ void __launch_bounds__(BLOCK, 2)
ealstm_kernel(const float* __restrict__ x_dd, const float* __restrict__ x_s,
              const float* __restrict__ bias, const float* __restrict__ w_in,
              const float* __restrict__ b_in, const float* __restrict__ w_dense,
              const float* __restrict__ b_dense,
              unsigned char* __restrict__ ws, float* __restrict__ out) {
  __shared__ __attribute__((aligned(16))) char zb[2 * ZBUF];
  __shared__ __attribute__((aligned(16))) char wih_l[G3 * DIN * 2];

  const unsigned short* whh_bf = (const unsigned short*)ws;
  const unsigned short* wih_bf = (const unsigned short*)(ws + WS_WIH);
  int*  flags = (int*)(ws + WS_FLAGS);
  char* pub   = (char*)(ws + WS_PUB);

  const int tid  = threadIdx.x;
  const int bid  = blockIdx.x;
  const int half = bid & 1;
  const int b0   = (bid >> 1) * 8;
  const int w    = tid >> 6;
  const int lane = tid & 63;
  const int m    = lane & 15;
  const int q    = lane >> 4;
  const int qh   = q >> 1;
  const int okb  = half * 4;        // own global k-octet base
  const int pkb  = okb ^ 4;         // partner k-octet base
  const int cbase = half * 128;     // own h-col base

  // stage Wih (swizzled) into LDS
  for (int i = tid; i < (G3 * DIN) / 8; i += BLOCK) {
    int g = i >> 2, qq = i & 3;
    bf16x8 v = *(const bf16x8*)(wih_bf + g * DIN + qq * 8);
    *(bf16x8*)(wih_l + g * 64 + ((qq ^ ((g >> 1) & 3)) << 4)) = v;
  }

  // zero own-h frags of buf0; stage x(0)
  if (tid < 128) *(f32x4*)(zb + tid * 16) = f32x4{0.f, 0.f, 0.f, 0.f};
  const int xrow = tid >> 5, xd = tid & 31;
  const int xoff = 2048 + (xd >> 3) * 128 + xrow * 16 + (xd & 7) * 2;
  const float* xq = x_dd + (size_t)(b0 + xrow) * DIN + xd;
  *(unsigned short*)(zb + xoff) = f2bf(xq[0]);
  xq += (size_t)BTOT * DIN;

  // Whh fragments: 6 tiles (f,g,o x 2 col-blocks) x 8 k-octets
  int gcol[6], wib[6];
  bf16x8 wr[6][8];
  #pragma unroll
  for (int s = 0; s < 6; ++s) {
    gcol[s] = (s % 3) * HD + cbase + (w + (s >= 3 ? 4 : 0)) * 16 + m;
    const unsigned short* wp = whh_bf + (size_t)gcol[s] * HD + q * 8;
    #pragma unroll
    for (int kk = 0; kk < 8; ++kk) wr[s][kk] = *(const bf16x8*)(wp + kk * 32);
    wib[s] = gcol[s] * 64 + ((q ^ ((m >> 1) & 3)) << 4);
  }
  float bv[6];
  #pragma unroll
  for (int s = 0; s < 6; ++s) bv[s] = bias[gcol[s]];

  // elementwise lane mapping + static input gate
  const int jl = (w + qh * 4) * 16 + m;     // own-local col 0..127
  const int jg = cbase + jl;
  float cst[4], ig[4];
  #pragma unroll
  for (int r = 0; r < 4; ++r) {
    int row = (q & 1) * 4 + r;
    float a = b_in[jg];
    const float* xr = x_s + (size_t)(b0 + row) * SIN;
    const float* wn = w_in + (size_t)jg * SIN;
    #pragma unroll
    for (int ss = 0; ss < SIN; ++ss) a += xr[ss] * wn[ss];
    ig[r] = fsig(a);
    cst[r] = 0.0f;
  }

  const int abase = q * 128 + (m & 7) * 16;
  const int wbo   = (jl >> 3) * 128 + (q & 1) * 64 + (jl & 7) * 2;
  int* flagO = flags + bid;
  int* flagP = flags + (bid ^ 1);

  for (int t = 0; t < TT; ++t) {
    if (t > 0 && tid == 0) {
      int spins = 0;
      while (__hip_atomic_load(flagP, __ATOMIC_ACQUIRE, __HIP_MEMORY_SCOPE_AGENT) < t) {
        __builtin_amdgcn_s_sleep(2);
        if (++spins > (1 << 26)) break;   // bounded: fail visibly, never hang
      }
    }
    __syncthreads();   // spin done + prev h/x LDS writes visible (t=0: init)

    // partner A-fragments (issued early to hide LLC latency under own MFMAs)
    bf16x8 pf0 = {}, pf1 = {}, pf2 = {}, pf3 = {};
    if (t > 0) {
      const char* pp = pub + (size_t)(((bid ^ 1) * 2) + (t & 1)) * 2048
                     + (m & 7) * 256 + q * 16;
      pf0 = *(const bf16x8*)(pp);
      pf1 = *(const bf16x8*)(pp + 64);
      pf2 = *(const bf16x8*)(pp + 128);
      pf3 = *(const bf16x8*)(pp + 192);
    }
    float xv = 0.0f;
    if (t + 1 < TT) xv = xq[0];

    const char* zc = zb + (t & 1) * ZBUF;
    f32x4 acc[6];
    #pragma unroll
    for (int s = 0; s < 6; ++s) acc[s] = f32x4{bv[s], bv[s], bv[s], bv[s]};

    #pragma unroll
    for (int o = 0; o < 4; ++o) {   // own half from LDS
      bf16x8 af = *(const bf16x8*)(zc + abase + o * 512);
      #pragma unroll
      for (int s = 0; s < 6; ++s)
        acc[s] = __builtin_amdgcn_mfma_f32_16x16x32_bf16(af, wr[s][okb + o], acc[s], 0, 0, 0);
    }
    {                               // x part
      bf16x8 ax = *(const bf16x8*)(zc + 2048 + abase);
      #pragma unroll
      for (int s = 0; s < 6; ++s) {
        bf16x8 wx = *(const bf16x8*)(wih_l + wib[s]);
        acc[s] = __builtin_amdgcn_mfma_f32_16x16x32_bf16(ax, wx, acc[s], 0, 0, 0);
      }
    }
    if (t > 0) {                    // partner half from regs (h(0)=0 -> skip at t=0)
      #pragma unroll
      for (int s = 0; s < 6; ++s)
        acc[s] = __builtin_amdgcn_mfma_f32_16x16x32_bf16(pf0, wr[s][pkb + 0], acc[s], 0, 0, 0);
      #pragma unroll
      for (int s = 0; s < 6; ++s)
        acc[s] = __builtin_amdgcn_mfma_f32_16x16x32_bf16(pf1, wr[s][pkb + 1], acc[s], 0, 0, 0);
      #pragma unroll
      for (int s = 0; s < 6; ++s)
        acc[s] = __builtin_amdgcn_mfma_f32_16x16x32_bf16(pf2, wr[s][pkb + 2], acc[s], 0, 0, 0);
      #pragma unroll
      for (int s = 0; s < 6; ++s)
        acc[s] = __builtin_amdgcn_mfma_f32_16x16x32_bf16(pf3, wr[s][pkb + 3], acc[s], 0, 0, 0);
    }

    // elementwise (q<2: tiles 0-2 / q>=2: tiles 3-5; D rows 8-15 dup 0-7)
    char* zn = zb + ((t + 1) & 1) * ZBUF;
    char* po = pub + (size_t)(bid * 2 + ((t + 1) & 1)) * 2048;
    const bool lastt = (t == TT - 1);
    #pragma unroll
    for (int r = 0; r < 4; ++r) {
      float pfv = (q < 2) ? acc[0][r] : acc[3][r];
      float pgv = (q < 2) ? acc[1][r] : acc[4][r];
      float pov = (q < 2) ? acc[2][r] : acc[5][r];
      float f  = fsig(pfv);
      float g  = ftanh(pgv);
      float o_ = fsig(pov);
      float c  = f * cst[r] + ig[r] * g;
      cst[r] = c;
      float h = o_ * ftanh(c);
      unsigned short hb = f2bf(h);
      *(unsigned short*)(zn + wbo + r * 16) = hb;
      if (!lastt) *(unsigned short*)(po + ((q & 1) * 4 + r) * 256 + jl * 2) = hb;
    }
    if (t + 1 < TT) {
      *(unsigned short*)(zn + xoff) = f2bf(xv);
      xq += (size_t)BTOT * DIN;
    }
    __syncthreads();   // all waves' LDS + pub stores drained (vmcnt pre-barrier)
    if (!lastt && tid == 0)
      __hip_atomic_store(flagO, t + 1, __ATOMIC_RELEASE, __HIP_MEMORY_SCOPE_AGENT);
  }

  // out[b] += sum_{j in own half} h[b][j]*w_dense[j]  (+ b_dense from even block)
  const char* hbuf = zb + (TT & 1) * ZBUF;
  if (tid < 64) {
    int row = tid >> 3, seg = tid & 7;
    float sum = 0.0f;
    #pragma unroll
    for (int jj = 0; jj < 16; ++jj) {
      int j = seg * 16 + jj;
      sum += bf2f(*(const unsigned short*)(hbuf + (j >> 3) * 128 + row * 16 + (j & 7) * 2))
             * w_dense[cbase + j];
    }
    sum += __shfl_xor(sum, 1, 64);
    sum += __shfl_xor(sum, 2, 64);
    sum += __shfl_xor(sum, 4, 64);
    if (seg == 0) {
      float v = sum + (half ? 0.0f : b_dense[0]);
      atomicAdd(out + b0 + row, v);
    }
  }
}

extern "C" void kernel_launch(void* const* d_in, const int* in_sizes, int n_in,
                              void* d_out, int out_size, void* d_ws, size_t ws_size,
                              hipStream_t stream) {
  (void)in_sizes; (void)n_in; (void)ws_size;
  const float* x_dd = (const float*)d_in[0];
  const float* x_s  = (const float*)d_in[1];
  const float* wih  = (const float*)d_in[2];
  const float* whh  = (const float*)d_in[3];
  const float* bias = (const float*)d_in[4];
  const float* w_in = (const float*)d_in[5];
  const float* b_in = (const float*)d_in[6];
  const float* w_d  = (const float*)d_in[7];
  const float* b_d  = (const float*)d_in[8];
  float* out = (float*)d_out;
  unsigned char* ws = (unsigned char*)d_ws;

  hipMemsetAsync(ws + WS_FLAGS, 0, 4096, stream);
  hipMemsetAsync(out, 0, (size_t)out_size * sizeof(float), stream);
  prep_kernel<<<128, 256, 0, stream>>>(whh, wih, (unsigned short*)ws,
                                       (unsigned short*)(ws + WS_WIH));
  ealstm_kernel<<<BTOT / 4, BLOCK, 0, stream>>>(
      x_dd, x_s, bias, w_in, b_in, w_d, b_d, ws, out);
}

// Round 5
// 763.201 us; speedup vs baseline: 15.0101x; 15.0101x over previous
//
#include <hip/hip_runtime.h>

#define TT   365
#define BTOT 2048
#define DIN  32
#define SIN  27
#define HD   256
#define G3   768
#define BLOCK 512
#define ZBUF 4608
#define XOFF 4096
#define WIHL_OFF 9216
#define L2E  1.442695040888963f

// ws layout (all written by prep): whh_bf16 | wih_bf16 | bias_scaled_f32
#define WS_WIH  (G3*HD*2)            // 393216
#define WS_BIAS (WS_WIH + G3*DIN*2)  // 442368

typedef float  f32x4  __attribute__((ext_vector_type(4)));
typedef short  bf16x8 __attribute__((ext_vector_type(8)));
typedef unsigned int u32x2 __attribute__((ext_vector_type(2)));

__device__ __forceinline__ unsigned short f2bf(float f) {
  unsigned u = __builtin_bit_cast(unsigned, f);
  u += 0x7fffu + ((u >> 16) & 1u);          // RNE to bf16
  return (unsigned short)(u >> 16);
}
__device__ __forceinline__ float bf2f(unsigned short u) {
  unsigned v = ((unsigned)u) << 16;
  return __builtin_bit_cast(float, v);
}

// prep: bf16-quantize weights with log2e folded (f,o rows x L2E; g rows x 2*L2E),
// and prescale bias the same way.
__global__ void prep_kernel(const float* __restrict__ whh, const float* __restrict__ wih,
                            const float* __restrict__ bias,
                            unsigned short* __restrict__ whh_bf,
                            unsigned short* __restrict__ wih_bf,
                            float* __restrict__ bias_s) {
  int stride = gridDim.x * blockDim.x;
  int i0 = blockIdx.x * blockDim.x + threadIdx.x;
  for (int i = i0; i < G3 * HD; i += stride) {
    int row = i >> 8;
    float s = (row >= HD && row < 2 * HD) ? 2.0f * L2E : L2E;
    whh_bf[i] = f2bf(whh[i] * s);
  }
  for (int i = i0; i < G3 * DIN; i += stride) {
    int row = i >> 5;
    float s = (row >= HD && row < 2 * HD) ? 2.0f * L2E : L2E;
    wih_bf[i] = f2bf(wih[i] * s);
  }
  for (int i = i0; i < G3; i += stride) {
    float s = (i >= HD && i < 2 * HD) ? 2.0f * L2E : L2E;
    bias_s[i] = bias[i] * s;
  }
}

// Persistent block per 8 batch rows. Transposed orientation:
// gates^T(768 x 8) = Whh~ (A, M=gate-rows, regs) x h^T (B, cols=batch, LDS).
// D: row=q*4+r = gate-col j, col=m = batch (m>=8 dup -> triple B).
// h LDS layout: byte(b,j) = b*512 + (j*2 ^ (b<<4)); x at XOFF + b*64 + d*2.
__global__ void __launch_bounds__(BLOCK, 2)
ealstm_kernel(const float* __restrict__ x_dd, const float* __restrict__ x_s,
              const float* __restrict__ w_in, const float* __restrict__ b_in,
              const float* __restrict__ w_dense, const float* __restrict__ b_dense,
              const unsigned short* __restrict__ whh_bf,
              const unsigned short* __restrict__ wih_bf,
              const float* __restrict__ bias_s,
              float* __restrict__ out) {
  __shared__ __attribute__((aligned(16))) char sm[WIHL_OFF + G3 * 64];  // 58368
  char* zb   = sm;            // 2 x 4608: h (4096) + x (512) per buffer
  char* wihl = sm + WIHL_OFF; // Wih~ rows, stride 64B

  const int tid  = threadIdx.x;
  const int b0   = blockIdx.x * 8;
  const int w    = tid >> 6;
  const int lane = tid & 63;
  const int m    = lane & 15;
  const int q    = lane >> 4;
  const int b    = m & 7;
  const int half = m >> 3;

  // stage Wih~ into LDS (row stride 64B)
  for (int i = tid; i < G3 * 4; i += BLOCK) {
    int row = i >> 2, qq = i & 3;
    *(bf16x8*)(wihl + row * 64 + qq * 16) = *(const bf16x8*)(wih_bf + row * DIN + qq * 8);
  }
  // zero h of buffer 0
  if (tid < 256) *(f32x4*)(zb + tid * 16) = f32x4{0.f, 0.f, 0.f, 0.f};
  // stage x(0)
  const int xr_ = tid >> 5, xd = tid & 31;
  const int xsoff = XOFF + xr_ * 64 + xd * 2;
  const float* xq = x_dd + (size_t)(b0 + xr_) * DIN + xd;
  if (tid < 256) *(unsigned short*)(zb + xsoff) = f2bf(xq[0]);
  xq += (size_t)BTOT * DIN;

  // Whh~ A-fragments: 6 tiles = (f,g,o) x (triple A @ w*16, triple B @ 128+w*16)
  const int sb0 = w * 16;
  bf16x8 wr[6][8];
  #pragma unroll
  for (int s = 0; s < 6; ++s) {
    int sbase = sb0 + (s >= 3 ? 128 : 0) + (s % 3) * 256;
    const unsigned short* wp = whh_bf + (size_t)(sbase + m) * HD + q * 8;
    #pragma unroll
    for (int kk = 0; kk < 8; ++kk) wr[s][kk] = *(const bf16x8*)(wp + kk * 32);
  }

  // per-lane (j, b) mapping: j = j0 + r, batch = b
  const int j0 = sb0 + half * 128 + q * 4;
  float cst[4], ig[4];
  #pragma unroll
  for (int r = 0; r < 4; ++r) {
    int j = j0 + r;
    float a = b_in[j];
    const float* xr = x_s + (size_t)(b0 + b) * SIN;
    const float* wn = w_in + (size_t)j * SIN;
    #pragma unroll
    for (int ss = 0; ss < SIN; ++ss) a += xr[ss] * wn[ss];
    ig[r] = __builtin_amdgcn_rcpf(1.0f + __builtin_amdgcn_exp2f(-a * L2E));
    cst[r] = 0.0f;
  }

  const int swz = b << 4;
  const int xrd = XOFF + b * 64 + q * 16;            // x B-frag (rel. buffer)
  const int hrb = b * 512;                           // h row base
  const int hq  = q * 16;
  const int hw  = b * 512 + ((j0 * 2) ^ swz);        // h write (rel. buffer)
  const float* bfp = bias_s + j0;
  const float* bgp = bias_s + 256 + j0;
  const float* bop = bias_s + 512 + j0;

  const f32x4 z4 = f32x4{0.f, 0.f, 0.f, 0.f};
  __syncthreads();

  for (int t = 0; t < TT; ++t) {
    char* zc = zb + (t & 1) * ZBUF;
    char* zn = zb + ((t + 1) & 1) * ZBUF;

    float xv = 0.0f;
    if (tid < 256 && t + 1 < TT) xv = xq[0];
    f32x4 bf4 = *(const f32x4*)bfp;                  // L1-hit reloads (prescaled)
    f32x4 bg4 = *(const f32x4*)bgp;
    f32x4 bo4 = *(const f32x4*)bop;

    // ---- MFMA chain: x-part first with C=0, then 8 h-octets ----
    bf16x8 xf = *(const bf16x8*)(zc + xrd);
    f32x4 acc0, acc1, acc2, acc3, acc4, acc5;
    {
      bf16x8 w0 = *(const bf16x8*)(wihl + (sb0       + m) * 64 + hq);
      bf16x8 w1 = *(const bf16x8*)(wihl + (sb0 + 256 + m) * 64 + hq);
      bf16x8 w2 = *(const bf16x8*)(wihl + (sb0 + 512 + m) * 64 + hq);
      bf16x8 w3 = *(const bf16x8*)(wihl + (sb0 + 128 + m) * 64 + hq);
      bf16x8 w4 = *(const bf16x8*)(wihl + (sb0 + 384 + m) * 64 + hq);
      bf16x8 w5 = *(const bf16x8*)(wihl + (sb0 + 640 + m) * 64 + hq);
      acc0 = __builtin_amdgcn_mfma_f32_16x16x32_bf16(w0, xf, z4, 0, 0, 0);
      acc1 = __builtin_amdgcn_mfma_f32_16x16x32_bf16(w1, xf, z4, 0, 0, 0);
      acc2 = __builtin_amdgcn_mfma_f32_16x16x32_bf16(w2, xf, z4, 0, 0, 0);
      acc3 = __builtin_amdgcn_mfma_f32_16x16x32_bf16(w3, xf, z4, 0, 0, 0);
      acc4 = __builtin_amdgcn_mfma_f32_16x16x32_bf16(w4, xf, z4, 0, 0, 0);
      acc5 = __builtin_amdgcn_mfma_f32_16x16x32_bf16(w5, xf, z4, 0, 0, 0);
    }
    #pragma unroll
    for (int kk = 0; kk < 8; ++kk) {
      bf16x8 hf = *(const bf16x8*)(zc + hrb + ((kk * 64 + hq) ^ swz));
      acc0 = __builtin_amdgcn_mfma_f32_16x16x32_bf16(wr[0][kk], hf, acc0, 0, 0, 0);
      acc1 = __builtin_amdgcn_mfma_f32_16x16x32_bf16(wr[1][kk], hf, acc1, 0, 0, 0);
      acc2 = __builtin_amdgcn_mfma_f32_16x16x32_bf16(wr[2][kk], hf, acc2, 0, 0, 0);
      acc3 = __builtin_amdgcn_mfma_f32_16x16x32_bf16(wr[3][kk], hf, acc3, 0, 0, 0);
      acc4 = __builtin_amdgcn_mfma_f32_16x16x32_bf16(wr[4][kk], hf, acc4, 0, 0, 0);
      acc5 = __builtin_amdgcn_mfma_f32_16x16x32_bf16(wr[5][kk], hf, acc5, 0, 0, 0);
    }

    // ---- elementwise: pre-activations already scaled by log2e (2*log2e for g) ----
    float h0, h1, h2, h3;
    #pragma unroll
    for (int r = 0; r < 4; ++r) {
      float pf = (half ? acc3[r] : acc0[r]) + bf4[r];
      float pg = (half ? acc4[r] : acc1[r]) + bg4[r];
      float po = (half ? acc5[r] : acc2[r]) + bo4[r];
      float fg = __builtin_amdgcn_rcpf(1.0f + __builtin_amdgcn_exp2f(-pf));
      float gg = 1.0f - 2.0f * __builtin_amdgcn_rcpf(1.0f + __builtin_amdgcn_exp2f(pg));
      float og = __builtin_amdgcn_rcpf(1.0f + __builtin_amdgcn_exp2f(-po));
      float c  = fg * cst[r] + ig[r] * gg;
      cst[r] = c;
      float th = 1.0f - 2.0f * __builtin_amdgcn_rcpf(1.0f + __builtin_amdgcn_exp2f(c * (2.0f * L2E)));
      float hv = og * th;
      if (r == 0) h0 = hv; else if (r == 1) h1 = hv; else if (r == 2) h2 = hv; else h3 = hv;
    }
    unsigned pk0, pk1;
    asm("v_cvt_pk_bf16_f32 %0, %1, %2" : "=v"(pk0) : "v"(h0), "v"(h1));
    asm("v_cvt_pk_bf16_f32 %0, %1, %2" : "=v"(pk1) : "v"(h2), "v"(h3));
    u32x2 pk = u32x2{pk0, pk1};
    *(u32x2*)(zn + hw) = pk;                         // one ds_write_b64

    if (tid < 256 && t + 1 < TT) {
      *(unsigned short*)(zn + xsoff) = f2bf(xv);
      xq += (size_t)BTOT * DIN;
    }
    __syncthreads();
  }

  // ---- output: out[b] = sum_j h[b][j] * w_dense[j] + b_dense[0] ----
  if (tid < 64) {
    const char* hb = zb + (TT & 1) * ZBUF;           // TT=365 -> buffer 1
    int row = tid >> 3, seg = tid & 7;
    float sum = 0.0f;
    #pragma unroll
    for (int jj = 0; jj < 32; ++jj) {
      int j = seg * 32 + jj;
      unsigned short hu = *(const unsigned short*)(hb + row * 512 + ((j * 2) ^ (row << 4)));
      sum += bf2f(hu) * w_dense[j];
    }
    sum += __shfl_xor(sum, 1, 64);
    sum += __shfl_xor(sum, 2, 64);
    sum += __shfl_xor(sum, 4, 64);
    if (seg == 0) out[b0 + row] = sum + b_dense[0];
  }
}

extern "C" void kernel_launch(void* const* d_in, const int* in_sizes, int n_in,
                              void* d_out, int out_size, void* d_ws, size_t ws_size,
                              hipStream_t stream) {
  (void)in_sizes; (void)n_in; (void)out_size; (void)ws_size;
  const float* x_dd = (const float*)d_in[0];
  const float* x_s  = (const float*)d_in[1];
  const float* wih  = (const float*)d_in[2];
  const float* whh  = (const float*)d_in[3];
  const float* bias = (const float*)d_in[4];
  const float* w_in = (const float*)d_in[5];
  const float* b_in = (const float*)d_in[6];
  const float* w_d  = (const float*)d_in[7];
  const float* b_d  = (const float*)d_in[8];
  float* out = (float*)d_out;
  unsigned char* ws = (unsigned char*)d_ws;

  unsigned short* whh_bf = (unsigned short*)ws;
  unsigned short* wih_bf = (unsigned short*)(ws + WS_WIH);
  float*          bias_s = (float*)(ws + WS_BIAS);

  prep_kernel<<<128, 256, 0, stream>>>(whh, wih, bias, whh_bf, wih_bf, bias_s);
  ealstm_kernel<<<BTOT / 8, BLOCK, 0, stream>>>(
      x_dd, x_s, w_in, b_in, w_d, b_d, whh_bf, wih_bf, bias_s, out);
}